// Round 1
// baseline (349.983 us; speedup 1.0000x reference)
//
#include <hip/hip_runtime.h>

typedef unsigned short u16;
typedef __bf16 bf16x8 __attribute__((ext_vector_type(8)));
typedef float f32x4 __attribute__((ext_vector_type(4)));

#define BB 2
#define TT 2048
#define CC 1024
#define HH 16
#define DD 64
#define MM (BB*TT)   // 4096

__device__ __forceinline__ u16 f2b(float f) {
    union { float f; unsigned int i; } a; a.f = f;
    unsigned int u = a.i;
    unsigned int r = (u + 0x7FFFu + ((u >> 16) & 1u)) >> 16;
    return (u16)r;
}
__device__ __forceinline__ u16 f2b_fast(float f) {
    union { float f; unsigned int i; } a; a.f = f;
    return (u16)((a.i + 0x8000u) >> 16);
}

// async global -> LDS, 16B per lane (dest must be wave-uniform base + lane*16)
__device__ __forceinline__ void gld16(const u16* g, u16* l) {
    __builtin_amdgcn_global_load_lds(
        (const __attribute__((address_space(1))) unsigned int*)g,
        (__attribute__((address_space(3))) unsigned int*)l, 16, 0, 0);
}

// ---------------- fp32 -> bf16 elementwise ----------------
__global__ __launch_bounds__(256) void cvt_x_k(const float* __restrict__ in,
                                               u16* __restrict__ out) {
    int i = blockIdx.x * 256 + threadIdx.x;
    float4 v = ((const float4*)in)[i];
    ushort4 o;
    o.x = f2b(v.x); o.y = f2b(v.y); o.z = f2b(v.z); o.w = f2b(v.w);
    ((ushort4*)out)[i] = o;
}

// ------ fp32 [K,N] -> bf16 [N,K] transpose+convert ------
__global__ __launch_bounds__(256) void transpose_cvt_k(const float* __restrict__ in,
                                                       u16* __restrict__ out,
                                                       int K, int N) {
    __shared__ u16 tile[64][65];
    int n0 = blockIdx.x * 64, k0 = blockIdx.y * 64;
    int tx = threadIdx.x, ty = threadIdx.y;   // (64,4)
    for (int i = 0; i < 16; i++) {
        int row = ty + i * 4;
        tile[row][tx] = f2b(in[(size_t)(k0 + row) * N + n0 + tx]);
    }
    __syncthreads();
    for (int i = 0; i < 16; i++) {
        int row = ty + i * 4;
        out[(size_t)(n0 + row) * K + k0 + tx] = tile[tx][row];
    }
}

// ------ bf16 per-bh transpose: v[bh][T][D] -> vt[bh][D][T] ------
__global__ __launch_bounds__(256) void transpose_v_k(const u16* __restrict__ in,
                                                     u16* __restrict__ out) {
    __shared__ u16 tile[64][65];
    int t0 = blockIdx.x * 64, bh = blockIdx.y;
    const u16* src = in + (size_t)bh * TT * DD;
    u16* dst = out + (size_t)bh * DD * TT;
    int tx = threadIdx.x, ty = threadIdx.y;
    for (int i = 0; i < 16; i++) {
        int row = ty + i * 4;
        tile[row][tx] = src[(size_t)(t0 + row) * DD + tx];
    }
    __syncthreads();
    for (int i = 0; i < 16; i++) {
        int row = ty + i * 4;
        dst[(size_t)row * TT + t0 + tx] = tile[tx][row];
    }
}

// ---------------- GEMM: C[M,N] = A[M,K] * Bt[N,K]^T ----------------
// MODE 0 epilogue pre-scales q by 0.125*log2(e) for the attn log2-softmax.
template<int MODE>
__global__ __launch_bounds__(256) void gemm_k(const u16* __restrict__ A,
                                              const u16* __restrict__ Bt,
                                              u16* __restrict__ Cq,
                                              u16* __restrict__ Ck,
                                              u16* __restrict__ Cv,
                                              float* __restrict__ Cout,
                                              int N, int K) {
    __shared__ __attribute__((aligned(16))) u16 As[128 * 32];
    __shared__ __attribute__((aligned(16))) u16 Bs[128 * 32];
    const int tid  = threadIdx.x;
    const int lane = tid & 63, w = tid >> 6;
    const int wm = w >> 1, wn = w & 1;
    const int quad = lane >> 4, l16 = lane & 15;
    const int m0 = blockIdx.x * 128, n0 = blockIdx.y * 128;

    f32x4 acc[4][4];
    for (int mi = 0; mi < 4; mi++)
        for (int ni = 0; ni < 4; ni++)
            for (int e = 0; e < 4; e++) acc[mi][ni][e] = 0.f;

    for (int k0 = 0; k0 < K; k0 += 32) {
        for (int i = 0; i < 2; i++) {
            int c = tid + 256 * i;
            int row = c >> 2, col = (c & 3) * 8;
            const u16* srcA;
            if constexpr (MODE == 0) {
                srcA = A + (size_t)(m0 + row) * K + k0 + col;
            } else {
                int m = m0 + row;
                int b = m >> 11, t = m & 2047;
                int kk = k0 + col;
                int h = kk >> 6, d = kk & 63;
                srcA = A + ((size_t)(b * HH + h) * TT + t) * DD + d;
            }
            gld16(srcA, &As[c * 8]);
            gld16(Bt + (size_t)(n0 + row) * K + k0 + col, &Bs[c * 8]);
        }
        __syncthreads();
        bf16x8 af[4], bfm[4];
        for (int mi = 0; mi < 4; mi++)
            af[mi] = *(const bf16x8*)&As[(wm * 64 + mi * 16 + l16) * 32 + quad * 8];
        for (int ni = 0; ni < 4; ni++)
            bfm[ni] = *(const bf16x8*)&Bs[(wn * 64 + ni * 16 + l16) * 32 + quad * 8];
        for (int mi = 0; mi < 4; mi++)
            for (int ni = 0; ni < 4; ni++)
                acc[mi][ni] = __builtin_amdgcn_mfma_f32_16x16x32_bf16(
                    af[mi], bfm[ni], acc[mi][ni], 0, 0, 0);
        __syncthreads();
    }

    const float SCQ = 0.125f * 1.44269504f;
    for (int mi = 0; mi < 4; mi++)
        for (int ni = 0; ni < 4; ni++)
            for (int r = 0; r < 4; r++) {
                int row = m0 + wm * 64 + mi * 16 + quad * 4 + r;
                int col = n0 + wn * 64 + ni * 16 + l16;
                if constexpr (MODE == 0) {
                    int which = col >> 10;
                    int h = (col >> 6) & 15, d = col & 63;
                    int b = row >> 11, t = row & 2047;
                    size_t off = ((size_t)(b * HH + h) * TT + t) * DD + d;
                    float val = acc[mi][ni][r];
                    if (which == 0) val *= SCQ;
                    (which == 0 ? Cq : which == 1 ? Ck : Cv)[off] = f2b(val);
                } else {
                    Cout[(size_t)row * N + col] = acc[mi][ni][r];
                }
            }
}

// ---------------- flash attention v5: one 64-row q-subtile per block ----------------
// Grid (bh=32, y=32) -> 1024 blocks = 4 blocks/CU (vs 2 before). blockIdx.x = bh
// so XCD = bh%8: each head's K/V stays resident in ONE XCD L2 (4 heads x 512KB = 2MB),
// and each CU's 4 resident blocks share the same bh (L1 reuse).
// y->sb mapping balances causal work: every CU's 4 resident blocks (y = g, g+8,
// g+16, g+24) sum to exactly 34 tile-passes.
// K fragments read directly from K [bh][T][D]; V fragments from Vt [bh][D][T].
// All 4 waves load identical kf/vf addresses -> L1 dedup. Only Ps lives in LDS
// (per-wave -> NO __syncthreads anywhere). First V quad prefetched before the
// softmax VALU phase so its latency hides under the exp2 chain.
__global__ __launch_bounds__(256, 4) void attn_k(const u16* __restrict__ Q,
                                                 const u16* __restrict__ Kb,
                                                 const u16* __restrict__ Vtg,
                                                 u16* __restrict__ Y) {
    __shared__ __attribute__((aligned(16))) u16 Ps[4][16 * 128];   // 16 KB
    const int tid  = threadIdx.x;
    const int lane = tid & 63, w = tid >> 6;
    const int quad = lane >> 4, l16 = lane & 15;
    const int bh = blockIdx.x;                 // 0..31 -> XCD = bh%8
    const int y  = blockIdx.y;                 // 0..31
    // work table: row=(y>>1)&3, col=y>>3 -> {16,9,8,1;15,10,7,2;14,11,6,3;13,12,5,4}
    const int rowi = (y >> 1) & 3, coli = y >> 3;
    const int basew = ((coli & 1) ? 9 : 16) - ((coli >> 1) << 3);
    const int work = basew + ((coli & 1) ? rowi : -rowi);   // = nkt = (sb>>1)+1
    const int sb = 2 * (work - 1) + (y & 1);
    const int nkt = work;
    const size_t base  = (size_t)bh * TT * DD;
    const size_t baseV = (size_t)bh * DD * TT;

    // Q fragments (A-layout, pre-scaled by 0.125*log2e in gemm0 epilogue)
    bf16x8 qf[2];
    for (int kk = 0; kk < 2; kk++)
        qf[kk] = *(const bf16x8*)(Q + base +
            (size_t)(sb * 64 + w * 16 + l16) * DD + kk * 32 + quad * 8);

    float mst[4], lst[4];
    f32x4 oacc[4];
    for (int r = 0; r < 4; r++) { mst[r] = -1e30f; lst[r] = 0.f; }
    for (int nd = 0; nd < 4; nd++)
        for (int e = 0; e < 4; e++) oacc[nd][e] = 0.f;

    for (int jk = 0; jk < nkt; jk++) {
        const u16* kb = Kb + base + (size_t)(jk * 128) * DD;

        // ---- S = Q K^T for one 64x128 subtile, kf streamed ----
        f32x4 s[8];
        for (int ni = 0; ni < 8; ni++)
            for (int e = 0; e < 4; e++) s[ni][e] = 0.f;
        for (int kk = 0; kk < 2; kk++) {
            bf16x8 kfa[8];
            for (int ni = 0; ni < 8; ni++)
                kfa[ni] = *(const bf16x8*)(kb +
                    (size_t)(ni * 16 + l16) * DD + kk * 32 + quad * 8);
            for (int ni = 0; ni < 8; ni++)
                s[ni] = __builtin_amdgcn_mfma_f32_16x16x32_bf16(
                    qf[kk], kfa[ni], s[ni], 0, 0, 0);
        }

        // ---- prefetch first V quad; latency hides under softmax VALU ----
        const u16* vb = Vtg + baseV + jk * 128;
        bf16x8 vpre[4];
        for (int nd = 0; nd < 4; nd++)
            vpre[nd] = *(const bf16x8*)(vb + (size_t)(nd * 16 + l16) * TT + quad * 8);

        // ---- online softmax (log2 domain) + Ps write ----
        if (jk == (sb >> 1)) {                 // diagonal tile: causal mask
            int row0 = sb * 64 + w * 16 + quad * 4;
            int col0 = jk * 128 + l16;
            for (int ni = 0; ni < 8; ni++)
                for (int r = 0; r < 4; r++)
                    if (col0 + ni * 16 > row0 + r) s[ni][r] = -1e30f;
        }
        float alpha[4];
        for (int r = 0; r < 4; r++) {
            float mx = s[0][r];
            for (int ni = 1; ni < 8; ni++) mx = fmaxf(mx, s[ni][r]);
            for (int off = 8; off >= 1; off >>= 1)
                mx = fmaxf(mx, __shfl_xor(mx, off));
            float mn = fmaxf(mst[r], mx);
            alpha[r] = __builtin_amdgcn_exp2f(mst[r] - mn);
            mst[r] = mn;
        }
        float rs[4] = {0.f, 0.f, 0.f, 0.f};
        for (int ni = 0; ni < 8; ni++)
            for (int r = 0; r < 4; r++) {
                float pv = __builtin_amdgcn_exp2f(s[ni][r] - mst[r]);
                rs[r] += pv;
                int row = quad * 4 + r;
                int cg  = ni * 2 + (l16 >> 3);
                Ps[w][row * 128 + ((cg ^ row) << 3) + (l16 & 7)] = f2b_fast(pv);
            }
        for (int r = 0; r < 4; r++) {
            float sm = rs[r];
            for (int off = 8; off >= 1; off >>= 1)
                sm += __shfl_xor(sm, off);
            lst[r] = lst[r] * alpha[r] + sm;
            for (int nd = 0; nd < 4; nd++) oacc[nd][r] *= alpha[r];
        }

        // ---- O += P V, vf streamed from Vt [bh][D][T] ----
        for (int kk = 0; kk < 4; kk++) {
            bf16x8 vfa[4];
            if (kk == 0) {
                for (int nd = 0; nd < 4; nd++) vfa[nd] = vpre[nd];
            } else {
                for (int nd = 0; nd < 4; nd++)
                    vfa[nd] = *(const bf16x8*)(vb +
                        (size_t)(nd * 16 + l16) * TT + kk * 32 + quad * 8);
            }
            bf16x8 pf = *(const bf16x8*)&Ps[w][l16 * 128 +
                (((kk * 4 + quad) ^ l16) << 3)];
            for (int nd = 0; nd < 4; nd++)
                oacc[nd] = __builtin_amdgcn_mfma_f32_16x16x32_bf16(
                    pf, vfa[nd], oacc[nd], 0, 0, 0);
        }
    }

    for (int nd = 0; nd < 4; nd++)
        for (int r = 0; r < 4; r++) {
            int row = sb * 64 + w * 16 + quad * 4 + r;
            int col = nd * 16 + l16;
            Y[base + (size_t)row * DD + col] = f2b(oacc[nd][r] / lst[r]);
        }
}

extern "C" void kernel_launch(void* const* d_in, const int* in_sizes, int n_in,
                              void* d_out, int out_size, void* d_ws, size_t ws_size,
                              hipStream_t stream) {
    const float* x      = (const float*)d_in[0];   // [2,2048,1024] fp32
    const float* W_attn = (const float*)d_in[1];   // [1024,3072]  fp32
    const float* W_proj = (const float*)d_in[2];   // [1024,1024]  fp32
    float* out = (float*)d_out;                    // [2,2048,1024] fp32

    u16* Wt_attn = (u16*)d_ws;                    // 3072*1024
    u16* Wt_proj = Wt_attn + 3072 * 1024;         // 1024*1024
    u16* xb      = Wt_proj + 1024 * 1024;         // 4096*1024 (reused as vt)
    u16* q       = xb + (size_t)MM * CC;
    u16* k       = q + (size_t)32 * 2048 * 64;
    u16* v       = k + (size_t)32 * 2048 * 64;
    u16* y       = v + (size_t)32 * 2048 * 64;
    u16* vt      = xb;                            // dead after gemm<0>

    cvt_x_k<<<dim3(MM * CC / 1024), 256, 0, stream>>>(x, xb);
    transpose_cvt_k<<<dim3(3072 / 64, 1024 / 64), dim3(64, 4), 0, stream>>>(
        W_attn, Wt_attn, 1024, 3072);
    transpose_cvt_k<<<dim3(1024 / 64, 1024 / 64), dim3(64, 4), 0, stream>>>(
        W_proj, Wt_proj, 1024, 1024);
    gemm_k<0><<<dim3(MM / 128, 3072 / 128), 256, 0, stream>>>(
        xb, Wt_attn, q, k, v, nullptr, 3072, 1024);
    transpose_v_k<<<dim3(TT / 64, BB * HH), dim3(64, 4), 0, stream>>>(v, vt);
    attn_k<<<dim3(32, 32), 256, 0, stream>>>(q, k, vt, y);
    gemm_k<1><<<dim3(MM / 128, 1024 / 128), 256, 0, stream>>>(
        y, Wt_proj, nullptr, nullptr, nullptr, out, 1024, 1024);
}

// Round 2
// 283.281 us; speedup vs baseline: 1.2355x; 1.2355x over previous
//
#include <hip/hip_runtime.h>

typedef unsigned short u16;
typedef __bf16 bf16x8 __attribute__((ext_vector_type(8)));
typedef float f32x4 __attribute__((ext_vector_type(4)));

#define BB 2
#define TT 2048
#define CC 1024
#define HH 16
#define DD 64
#define MM (BB*TT)   // 4096

__device__ __forceinline__ u16 f2b(float f) {
    union { float f; unsigned int i; } a; a.f = f;
    unsigned int u = a.i;
    unsigned int r = (u + 0x7FFFu + ((u >> 16) & 1u)) >> 16;
    return (u16)r;
}
__device__ __forceinline__ u16 f2b_fast(float f) {
    union { float f; unsigned int i; } a; a.f = f;
    return (u16)((a.i + 0x8000u) >> 16);
}

// async global -> LDS, 16B per lane (dest must be wave-uniform base + lane*16)
__device__ __forceinline__ void gld16(const u16* g, u16* l) {
    __builtin_amdgcn_global_load_lds(
        (const __attribute__((address_space(1))) unsigned int*)g,
        (__attribute__((address_space(3))) unsigned int*)l, 16, 0, 0);
}

// ---------------- fp32 -> bf16 elementwise ----------------
__global__ __launch_bounds__(256) void cvt_x_k(const float* __restrict__ in,
                                               u16* __restrict__ out) {
    int i = blockIdx.x * 256 + threadIdx.x;
    float4 v = ((const float4*)in)[i];
    ushort4 o;
    o.x = f2b(v.x); o.y = f2b(v.y); o.z = f2b(v.z); o.w = f2b(v.w);
    ((ushort4*)out)[i] = o;
}

// ------ fp32 [K,N] -> bf16 [N,K] transpose+convert ------
__global__ __launch_bounds__(256) void transpose_cvt_k(const float* __restrict__ in,
                                                       u16* __restrict__ out,
                                                       int K, int N) {
    __shared__ u16 tile[64][65];
    int n0 = blockIdx.x * 64, k0 = blockIdx.y * 64;
    int tx = threadIdx.x, ty = threadIdx.y;   // (64,4)
    for (int i = 0; i < 16; i++) {
        int row = ty + i * 4;
        tile[row][tx] = f2b(in[(size_t)(k0 + row) * N + n0 + tx]);
    }
    __syncthreads();
    for (int i = 0; i < 16; i++) {
        int row = ty + i * 4;
        out[(size_t)(n0 + row) * K + k0 + tx] = tile[tx][row];
    }
}

// ------ bf16 per-bh transpose: v[bh][T][D] -> vt[bh][D][T] ------
__global__ __launch_bounds__(256) void transpose_v_k(const u16* __restrict__ in,
                                                     u16* __restrict__ out) {
    __shared__ u16 tile[64][65];
    int t0 = blockIdx.x * 64, bh = blockIdx.y;
    const u16* src = in + (size_t)bh * TT * DD;
    u16* dst = out + (size_t)bh * DD * TT;
    int tx = threadIdx.x, ty = threadIdx.y;
    for (int i = 0; i < 16; i++) {
        int row = ty + i * 4;
        tile[row][tx] = src[(size_t)(t0 + row) * DD + tx];
    }
    __syncthreads();
    for (int i = 0; i < 16; i++) {
        int row = ty + i * 4;
        dst[(size_t)row * TT + t0 + tx] = tile[tx][row];
    }
}

// ---------------- GEMM: C[M,N] = A[M,K] * Bt[N,K]^T ----------------
// MODE 0 epilogue pre-scales q by 0.125*log2(e) for the attn log2-softmax.
template<int MODE>
__global__ __launch_bounds__(256) void gemm_k(const u16* __restrict__ A,
                                              const u16* __restrict__ Bt,
                                              u16* __restrict__ Cq,
                                              u16* __restrict__ Ck,
                                              u16* __restrict__ Cv,
                                              float* __restrict__ Cout,
                                              int N, int K) {
    __shared__ __attribute__((aligned(16))) u16 As[128 * 32];
    __shared__ __attribute__((aligned(16))) u16 Bs[128 * 32];
    const int tid  = threadIdx.x;
    const int lane = tid & 63, w = tid >> 6;
    const int wm = w >> 1, wn = w & 1;
    const int quad = lane >> 4, l16 = lane & 15;
    const int m0 = blockIdx.x * 128, n0 = blockIdx.y * 128;

    f32x4 acc[4][4];
    for (int mi = 0; mi < 4; mi++)
        for (int ni = 0; ni < 4; ni++)
            for (int e = 0; e < 4; e++) acc[mi][ni][e] = 0.f;

    for (int k0 = 0; k0 < K; k0 += 32) {
        for (int i = 0; i < 2; i++) {
            int c = tid + 256 * i;
            int row = c >> 2, col = (c & 3) * 8;
            const u16* srcA;
            if constexpr (MODE == 0) {
                srcA = A + (size_t)(m0 + row) * K + k0 + col;
            } else {
                int m = m0 + row;
                int b = m >> 11, t = m & 2047;
                int kk = k0 + col;
                int h = kk >> 6, d = kk & 63;
                srcA = A + ((size_t)(b * HH + h) * TT + t) * DD + d;
            }
            gld16(srcA, &As[c * 8]);
            gld16(Bt + (size_t)(n0 + row) * K + k0 + col, &Bs[c * 8]);
        }
        __syncthreads();
        bf16x8 af[4], bfm[4];
        for (int mi = 0; mi < 4; mi++)
            af[mi] = *(const bf16x8*)&As[(wm * 64 + mi * 16 + l16) * 32 + quad * 8];
        for (int ni = 0; ni < 4; ni++)
            bfm[ni] = *(const bf16x8*)&Bs[(wn * 64 + ni * 16 + l16) * 32 + quad * 8];
        for (int mi = 0; mi < 4; mi++)
            for (int ni = 0; ni < 4; ni++)
                acc[mi][ni] = __builtin_amdgcn_mfma_f32_16x16x32_bf16(
                    af[mi], bfm[ni], acc[mi][ni], 0, 0, 0);
        __syncthreads();
    }

    const float SCQ = 0.125f * 1.44269504f;
    for (int mi = 0; mi < 4; mi++)
        for (int ni = 0; ni < 4; ni++)
            for (int r = 0; r < 4; r++) {
                int row = m0 + wm * 64 + mi * 16 + quad * 4 + r;
                int col = n0 + wn * 64 + ni * 16 + l16;
                if constexpr (MODE == 0) {
                    int which = col >> 10;
                    int h = (col >> 6) & 15, d = col & 63;
                    int b = row >> 11, t = row & 2047;
                    size_t off = ((size_t)(b * HH + h) * TT + t) * DD + d;
                    float val = acc[mi][ni][r];
                    if (which == 0) val *= SCQ;
                    (which == 0 ? Cq : which == 1 ? Ck : Cv)[off] = f2b(val);
                } else {
                    Cout[(size_t)row * N + col] = acc[mi][ni][r];
                }
            }
}

// ---------------- flash attention v6: v5 structure, spill-free register cap ----------------
// Grid (bh=32, y=32) -> 1024 blocks = up to 4 blocks/CU. blockIdx.x = bh so
// XCD = bh%8: each head's K/V stays resident in ONE XCD L2, and co-resident
// blocks on a CU share the same bh (L1 reuse).
// y->sb mapping balances causal work: resident quads sum to 34 tile-passes.
// __launch_bounds__(256,3): VGPR cap 170 — fits the ~120-reg working set with
// NO scratch spill (the (256,4)/64-VGPR variant spilled 42 MB to scratch).
__global__ __launch_bounds__(256, 3) void attn_k(const u16* __restrict__ Q,
                                                 const u16* __restrict__ Kb,
                                                 const u16* __restrict__ Vtg,
                                                 u16* __restrict__ Y) {
    __shared__ __attribute__((aligned(16))) u16 Ps[4][16 * 128];   // 16 KB
    const int tid  = threadIdx.x;
    const int lane = tid & 63, w = tid >> 6;
    const int quad = lane >> 4, l16 = lane & 15;
    const int bh = blockIdx.x;                 // 0..31 -> XCD = bh%8
    const int y  = blockIdx.y;                 // 0..31
    // work table: row=(y>>1)&3, col=y>>3 -> {16,9,8,1;15,10,7,2;14,11,6,3;13,12,5,4}
    const int rowi = (y >> 1) & 3, coli = y >> 3;
    const int basew = ((coli & 1) ? 9 : 16) - ((coli >> 1) << 3);
    const int work = basew + ((coli & 1) ? rowi : -rowi);   // = nkt = (sb>>1)+1
    const int sb = 2 * (work - 1) + (y & 1);
    const int nkt = work;
    const size_t base  = (size_t)bh * TT * DD;
    const size_t baseV = (size_t)bh * DD * TT;

    // Q fragments (A-layout, pre-scaled by 0.125*log2e in gemm0 epilogue)
    bf16x8 qf[2];
    for (int kk = 0; kk < 2; kk++)
        qf[kk] = *(const bf16x8*)(Q + base +
            (size_t)(sb * 64 + w * 16 + l16) * DD + kk * 32 + quad * 8);

    float mst[4], lst[4];
    f32x4 oacc[4];
    for (int r = 0; r < 4; r++) { mst[r] = -1e30f; lst[r] = 0.f; }
    for (int nd = 0; nd < 4; nd++)
        for (int e = 0; e < 4; e++) oacc[nd][e] = 0.f;

    for (int jk = 0; jk < nkt; jk++) {
        const u16* kb = Kb + base + (size_t)(jk * 128) * DD;

        // ---- S = Q K^T for one 64x128 subtile, kf streamed ----
        f32x4 s[8];
        for (int ni = 0; ni < 8; ni++)
            for (int e = 0; e < 4; e++) s[ni][e] = 0.f;
        for (int kk = 0; kk < 2; kk++) {
            bf16x8 kfa[8];
            for (int ni = 0; ni < 8; ni++)
                kfa[ni] = *(const bf16x8*)(kb +
                    (size_t)(ni * 16 + l16) * DD + kk * 32 + quad * 8);
            for (int ni = 0; ni < 8; ni++)
                s[ni] = __builtin_amdgcn_mfma_f32_16x16x32_bf16(
                    qf[kk], kfa[ni], s[ni], 0, 0, 0);
        }

        // ---- prefetch first V quad; latency hides under softmax VALU ----
        const u16* vb = Vtg + baseV + jk * 128;
        bf16x8 vpre[4];
        for (int nd = 0; nd < 4; nd++)
            vpre[nd] = *(const bf16x8*)(vb + (size_t)(nd * 16 + l16) * TT + quad * 8);

        // ---- online softmax (log2 domain) + Ps write ----
        if (jk == (sb >> 1)) {                 // diagonal tile: causal mask
            int row0 = sb * 64 + w * 16 + quad * 4;
            int col0 = jk * 128 + l16;
            for (int ni = 0; ni < 8; ni++)
                for (int r = 0; r < 4; r++)
                    if (col0 + ni * 16 > row0 + r) s[ni][r] = -1e30f;
        }
        float alpha[4];
        for (int r = 0; r < 4; r++) {
            float mx = s[0][r];
            for (int ni = 1; ni < 8; ni++) mx = fmaxf(mx, s[ni][r]);
            for (int off = 8; off >= 1; off >>= 1)
                mx = fmaxf(mx, __shfl_xor(mx, off));
            float mn = fmaxf(mst[r], mx);
            alpha[r] = __builtin_amdgcn_exp2f(mst[r] - mn);
            mst[r] = mn;
        }
        float rs[4] = {0.f, 0.f, 0.f, 0.f};
        for (int ni = 0; ni < 8; ni++)
            for (int r = 0; r < 4; r++) {
                float pv = __builtin_amdgcn_exp2f(s[ni][r] - mst[r]);
                rs[r] += pv;
                int row = quad * 4 + r;
                int cg  = ni * 2 + (l16 >> 3);
                Ps[w][row * 128 + ((cg ^ row) << 3) + (l16 & 7)] = f2b_fast(pv);
            }
        for (int r = 0; r < 4; r++) {
            float sm = rs[r];
            for (int off = 8; off >= 1; off >>= 1)
                sm += __shfl_xor(sm, off);
            lst[r] = lst[r] * alpha[r] + sm;
            for (int nd = 0; nd < 4; nd++) oacc[nd][r] *= alpha[r];
        }

        // ---- O += P V, vf streamed from Vt [bh][D][T] ----
        for (int kk = 0; kk < 4; kk++) {
            bf16x8 vfa[4];
            if (kk == 0) {
                for (int nd = 0; nd < 4; nd++) vfa[nd] = vpre[nd];
            } else {
                for (int nd = 0; nd < 4; nd++)
                    vfa[nd] = *(const bf16x8*)(vb +
                        (size_t)(nd * 16 + l16) * TT + kk * 32 + quad * 8);
            }
            bf16x8 pf = *(const bf16x8*)&Ps[w][l16 * 128 +
                (((kk * 4 + quad) ^ l16) << 3)];
            for (int nd = 0; nd < 4; nd++)
                oacc[nd] = __builtin_amdgcn_mfma_f32_16x16x32_bf16(
                    pf, vfa[nd], oacc[nd], 0, 0, 0);
        }
    }

    for (int nd = 0; nd < 4; nd++)
        for (int r = 0; r < 4; r++) {
            int row = sb * 64 + w * 16 + quad * 4 + r;
            int col = nd * 16 + l16;
            Y[base + (size_t)row * DD + col] = f2b(oacc[nd][r] / lst[r]);
        }
}

extern "C" void kernel_launch(void* const* d_in, const int* in_sizes, int n_in,
                              void* d_out, int out_size, void* d_ws, size_t ws_size,
                              hipStream_t stream) {
    const float* x      = (const float*)d_in[0];   // [2,2048,1024] fp32
    const float* W_attn = (const float*)d_in[1];   // [1024,3072]  fp32
    const float* W_proj = (const float*)d_in[2];   // [1024,1024]  fp32
    float* out = (float*)d_out;                    // [2,2048,1024] fp32

    u16* Wt_attn = (u16*)d_ws;                    // 3072*1024
    u16* Wt_proj = Wt_attn + 3072 * 1024;         // 1024*1024
    u16* xb      = Wt_proj + 1024 * 1024;         // 4096*1024 (reused as vt)
    u16* q       = xb + (size_t)MM * CC;
    u16* k       = q + (size_t)32 * 2048 * 64;
    u16* v       = k + (size_t)32 * 2048 * 64;
    u16* y       = v + (size_t)32 * 2048 * 64;
    u16* vt      = xb;                            // dead after gemm<0>

    cvt_x_k<<<dim3(MM * CC / 1024), 256, 0, stream>>>(x, xb);
    transpose_cvt_k<<<dim3(3072 / 64, 1024 / 64), dim3(64, 4), 0, stream>>>(
        W_attn, Wt_attn, 1024, 3072);
    transpose_cvt_k<<<dim3(1024 / 64, 1024 / 64), dim3(64, 4), 0, stream>>>(
        W_proj, Wt_proj, 1024, 1024);
    gemm_k<0><<<dim3(MM / 128, 3072 / 128), 256, 0, stream>>>(
        xb, Wt_attn, q, k, v, nullptr, 3072, 1024);
    transpose_v_k<<<dim3(TT / 64, BB * HH), dim3(64, 4), 0, stream>>>(v, vt);
    attn_k<<<dim3(32, 32), 256, 0, stream>>>(q, k, vt, y);
    gemm_k<1><<<dim3(MM / 128, 1024 / 128), 256, 0, stream>>>(
        y, Wt_proj, nullptr, nullptr, nullptr, out, 1024, 1024);
}

// Round 3
// 201.648 us; speedup vs baseline: 1.7356x; 1.4048x over previous
//
#include <hip/hip_runtime.h>

typedef unsigned short u16;
typedef __bf16 bf16x8 __attribute__((ext_vector_type(8)));
typedef float f32x4 __attribute__((ext_vector_type(4)));

#define BB 2
#define TT 2048
#define CC 1024
#define HH 16
#define DD 64
#define MM (BB*TT)   // 4096

__device__ __forceinline__ u16 f2b(float f) {
    union { float f; unsigned int i; } a; a.f = f;
    unsigned int u = a.i;
    unsigned int r = (u + 0x7FFFu + ((u >> 16) & 1u)) >> 16;
    return (u16)r;
}
__device__ __forceinline__ u16 f2b_fast(float f) {
    union { float f; unsigned int i; } a; a.f = f;
    return (u16)((a.i + 0x8000u) >> 16);
}

// async global -> LDS, 16B per lane (dest must be wave-uniform base + lane*16)
__device__ __forceinline__ void gld16(const u16* g, u16* l) {
    __builtin_amdgcn_global_load_lds(
        (const __attribute__((address_space(1))) unsigned int*)g,
        (__attribute__((address_space(3))) unsigned int*)l, 16, 0, 0);
}

// ---------------- fp32 -> bf16 elementwise ----------------
__global__ __launch_bounds__(256) void cvt_x_k(const float* __restrict__ in,
                                               u16* __restrict__ out) {
    int i = blockIdx.x * 256 + threadIdx.x;
    float4 v = ((const float4*)in)[i];
    ushort4 o;
    o.x = f2b(v.x); o.y = f2b(v.y); o.z = f2b(v.z); o.w = f2b(v.w);
    ((ushort4*)out)[i] = o;
}

// ------ fp32 [K,N] -> bf16 [N,K] transpose+convert ------
__global__ __launch_bounds__(256) void transpose_cvt_k(const float* __restrict__ in,
                                                       u16* __restrict__ out,
                                                       int K, int N) {
    __shared__ u16 tile[64][65];
    int n0 = blockIdx.x * 64, k0 = blockIdx.y * 64;
    int tx = threadIdx.x, ty = threadIdx.y;   // (64,4)
    for (int i = 0; i < 16; i++) {
        int row = ty + i * 4;
        tile[row][tx] = f2b(in[(size_t)(k0 + row) * N + n0 + tx]);
    }
    __syncthreads();
    for (int i = 0; i < 16; i++) {
        int row = ty + i * 4;
        out[(size_t)(n0 + row) * K + k0 + tx] = tile[tx][row];
    }
}

// ------ bf16 per-bh transpose: v[bh][T][D] -> vt[bh][D][T] ------
__global__ __launch_bounds__(256) void transpose_v_k(const u16* __restrict__ in,
                                                     u16* __restrict__ out) {
    __shared__ u16 tile[64][65];
    int t0 = blockIdx.x * 64, bh = blockIdx.y;
    const u16* src = in + (size_t)bh * TT * DD;
    u16* dst = out + (size_t)bh * DD * TT;
    int tx = threadIdx.x, ty = threadIdx.y;
    for (int i = 0; i < 16; i++) {
        int row = ty + i * 4;
        tile[row][tx] = src[(size_t)(t0 + row) * DD + tx];
    }
    __syncthreads();
    for (int i = 0; i < 16; i++) {
        int row = ty + i * 4;
        dst[(size_t)row * TT + t0 + tx] = tile[tx][row];
    }
}

// ---------------- GEMM: C[M,N] = A[M,K] * Bt[N,K]^T ----------------
// MODE 0 epilogue pre-scales q by 0.125*log2(e) for the attn log2-softmax.
template<int MODE>
__global__ __launch_bounds__(256) void gemm_k(const u16* __restrict__ A,
                                              const u16* __restrict__ Bt,
                                              u16* __restrict__ Cq,
                                              u16* __restrict__ Ck,
                                              u16* __restrict__ Cv,
                                              float* __restrict__ Cout,
                                              int N, int K) {
    __shared__ __attribute__((aligned(16))) u16 As[128 * 32];
    __shared__ __attribute__((aligned(16))) u16 Bs[128 * 32];
    const int tid  = threadIdx.x;
    const int lane = tid & 63, w = tid >> 6;
    const int wm = w >> 1, wn = w & 1;
    const int quad = lane >> 4, l16 = lane & 15;
    const int m0 = blockIdx.x * 128, n0 = blockIdx.y * 128;

    f32x4 acc[4][4];
    for (int mi = 0; mi < 4; mi++)
        for (int ni = 0; ni < 4; ni++)
            for (int e = 0; e < 4; e++) acc[mi][ni][e] = 0.f;

    for (int k0 = 0; k0 < K; k0 += 32) {
        for (int i = 0; i < 2; i++) {
            int c = tid + 256 * i;
            int row = c >> 2, col = (c & 3) * 8;
            const u16* srcA;
            if constexpr (MODE == 0) {
                srcA = A + (size_t)(m0 + row) * K + k0 + col;
            } else {
                int m = m0 + row;
                int b = m >> 11, t = m & 2047;
                int kk = k0 + col;
                int h = kk >> 6, d = kk & 63;
                srcA = A + ((size_t)(b * HH + h) * TT + t) * DD + d;
            }
            gld16(srcA, &As[c * 8]);
            gld16(Bt + (size_t)(n0 + row) * K + k0 + col, &Bs[c * 8]);
        }
        __syncthreads();
        bf16x8 af[4], bfm[4];
        for (int mi = 0; mi < 4; mi++)
            af[mi] = *(const bf16x8*)&As[(wm * 64 + mi * 16 + l16) * 32 + quad * 8];
        for (int ni = 0; ni < 4; ni++)
            bfm[ni] = *(const bf16x8*)&Bs[(wn * 64 + ni * 16 + l16) * 32 + quad * 8];
        for (int mi = 0; mi < 4; mi++)
            for (int ni = 0; ni < 4; ni++)
                acc[mi][ni] = __builtin_amdgcn_mfma_f32_16x16x32_bf16(
                    af[mi], bfm[ni], acc[mi][ni], 0, 0, 0);
        __syncthreads();
    }

    const float SCQ = 0.125f * 1.44269504f;
    for (int mi = 0; mi < 4; mi++)
        for (int ni = 0; ni < 4; ni++)
            for (int r = 0; r < 4; r++) {
                int row = m0 + wm * 64 + mi * 16 + quad * 4 + r;
                int col = n0 + wn * 64 + ni * 16 + l16;
                if constexpr (MODE == 0) {
                    int which = col >> 10;
                    int h = (col >> 6) & 15, d = col & 63;
                    int b = row >> 11, t = row & 2047;
                    size_t off = ((size_t)(b * HH + h) * TT + t) * DD + d;
                    float val = acc[mi][ni][r];
                    if (which == 0) val *= SCQ;
                    (which == 0 ? Cq : which == 1 ? Ck : Cv)[off] = f2b(val);
                } else {
                    Cout[(size_t)row * N + col] = acc[mi][ni][r];
                }
            }
}

// ---------------- flash attention v7: LDS-staged K/V, software-pipelined ----------------
// Grid (bh=32, y=32); XCD = bh%8 keeps each head's K/V in one XCD L2.
// Per pass: K tile [128][64] and V tile [64][128] staged via global_load_lds
// (4 gld16/wave each = async DMA, 4x dedup across waves vs per-lane reg loads).
// K double-buffered (consumed at pass top; next tile staged right after B1);
// V single-buffered (consumed at pass end; next tile staged after B2 post-PV,
// lands during the next pass). XOR swizzle slot^=(row&7), applied BOTH on the
// pre-swizzled global source (LDS dest stays linear for the DMA) and on the
// ds_read_b128 address -> 2-way max bank aliasing (free).
// LDS: 2*16K (K) + 16K (V) + 16K (Ps) = 64 KB -> 2 blocks/CU.
// __launch_bounds__(256,2): 256-VGPR budget, no spill (R1 lesson).
__global__ __launch_bounds__(256, 2) void attn_k(const u16* __restrict__ Q,
                                                 const u16* __restrict__ Kb,
                                                 const u16* __restrict__ Vtg,
                                                 u16* __restrict__ Y) {
    __shared__ __attribute__((aligned(16))) u16 Ks[2][128 * 64];  // 32 KB
    __shared__ __attribute__((aligned(16))) u16 Vs[64 * 128];     // 16 KB
    __shared__ __attribute__((aligned(16))) u16 Ps[4][16 * 128];  // 16 KB
    const int tid  = threadIdx.x;
    const int lane = tid & 63, w = tid >> 6;
    const int quad = lane >> 4, l16 = lane & 15;
    const int bh = blockIdx.x;                 // 0..31 -> XCD = bh%8
    const int y  = blockIdx.y;                 // 0..31
    // work table balances causal load: work = nkt = (sb>>1)+1
    const int rowi = (y >> 1) & 3, coli = y >> 3;
    const int basew = ((coli & 1) ? 9 : 16) - ((coli >> 1) << 3);
    const int work = basew + ((coli & 1) ? rowi : -rowi);
    const int sb = 2 * (work - 1) + (y & 1);
    const int nkt = work;
    const size_t base  = (size_t)bh * TT * DD;
    const size_t baseV = (size_t)bh * DD * TT;

    // per-lane staging offsets: 4 rounds x 256 lanes cover 1024 16B-slots/tile.
    // K tile: sidx = row*8 + slot  (row 0..127, 8 slots of 16B per 128B row)
    // V tile: sidx = row*16 + slot (row 0..63, 16 slots of 16B per 256B row)
    // content swizzle: LDS slot s of row holds global col-group s^(row&7).
    int ksidx[4], koff[4], voff[4];
    for (int r = 0; r < 4; r++) {
        int sidx = r * 256 + tid;
        ksidx[r] = sidx;
        int kr = sidx >> 3, ksl = sidx & 7;
        koff[r] = kr * 64 + ((ksl ^ (kr & 7)) << 3);
        int vr = sidx >> 4, vsl = sidx & 15;
        voff[r] = vr * TT + ((vsl ^ (vr & 7)) << 3);
    }
    const u16* kg = Kb + base;      // + jk*8192 + koff[r]
    const u16* vg = Vtg + baseV;    // + jk*128  + voff[r]

    // prologue: stage tile 0
    for (int r = 0; r < 4; r++) gld16(kg + koff[r], &Ks[0][ksidx[r] * 8]);
    for (int r = 0; r < 4; r++) gld16(vg + voff[r], &Vs[ksidx[r] * 8]);

    // Q fragments (A-layout, pre-scaled by 0.125*log2e in gemm0 epilogue)
    bf16x8 qf[2];
    for (int kk = 0; kk < 2; kk++)
        qf[kk] = *(const bf16x8*)(Q + base +
            (size_t)(sb * 64 + w * 16 + l16) * DD + kk * 32 + quad * 8);

    // ds_read swizzled slot offsets (u16 elements)
    const int swx = (l16 & 7);
    const int swk0 = ((quad ^ swx) << 3);
    const int swk1 = (((4 + quad) ^ swx) << 3);

    float mst[4], lst[4];
    f32x4 oacc[4];
    for (int r = 0; r < 4; r++) { mst[r] = -1e30f; lst[r] = 0.f; }
    for (int nd = 0; nd < 4; nd++)
        for (int e = 0; e < 4; e++) oacc[nd][e] = 0.f;

    for (int jk = 0; jk < nkt; jk++) {
        const int cb = jk & 1;
        __syncthreads();   // B1: K[jk] + V[jk] staged & visible; Ks[cb^1] free

        // stage next K tile (lands during this pass)
        if (jk + 1 < nkt) {
            const u16* kn = kg + (size_t)(jk + 1) * (128 * DD);
            for (int r = 0; r < 4; r++)
                gld16(kn + koff[r], &Ks[cb ^ 1][ksidx[r] * 8]);
        }

        // ---- S = Q K^T from LDS (swizzled ds_read_b128) ----
        f32x4 s[8];
        for (int ni = 0; ni < 8; ni++)
            for (int e = 0; e < 4; e++) s[ni][e] = 0.f;
        {
            bf16x8 kfa[8];
            for (int ni = 0; ni < 8; ni++)
                kfa[ni] = *(const bf16x8*)&Ks[cb][(ni * 16 + l16) * 64 + swk0];
            for (int ni = 0; ni < 8; ni++)
                s[ni] = __builtin_amdgcn_mfma_f32_16x16x32_bf16(
                    qf[0], kfa[ni], s[ni], 0, 0, 0);
        }
        {
            bf16x8 kfa[8];
            for (int ni = 0; ni < 8; ni++)
                kfa[ni] = *(const bf16x8*)&Ks[cb][(ni * 16 + l16) * 64 + swk1];
            for (int ni = 0; ni < 8; ni++)
                s[ni] = __builtin_amdgcn_mfma_f32_16x16x32_bf16(
                    qf[1], kfa[ni], s[ni], 0, 0, 0);
        }

        // ---- online softmax (log2 domain) + Ps write ----
        if (jk == (sb >> 1)) {                 // diagonal tile: causal mask
            int row0 = sb * 64 + w * 16 + quad * 4;
            int col0 = jk * 128 + l16;
            for (int ni = 0; ni < 8; ni++)
                for (int r = 0; r < 4; r++)
                    if (col0 + ni * 16 > row0 + r) s[ni][r] = -1e30f;
        }
        float alpha[4];
        for (int r = 0; r < 4; r++) {
            float mx = s[0][r];
            for (int ni = 1; ni < 8; ni++) mx = fmaxf(mx, s[ni][r]);
            for (int off = 8; off >= 1; off >>= 1)
                mx = fmaxf(mx, __shfl_xor(mx, off));
            float mn = fmaxf(mst[r], mx);
            alpha[r] = __builtin_amdgcn_exp2f(mst[r] - mn);
            mst[r] = mn;
        }
        float rs[4] = {0.f, 0.f, 0.f, 0.f};
        for (int ni = 0; ni < 8; ni++)
            for (int r = 0; r < 4; r++) {
                float pv = __builtin_amdgcn_exp2f(s[ni][r] - mst[r]);
                rs[r] += pv;
                int row = quad * 4 + r;
                int cg  = ni * 2 + (l16 >> 3);
                Ps[w][row * 128 + ((cg ^ row) << 3) + (l16 & 7)] = f2b_fast(pv);
            }
        for (int r = 0; r < 4; r++) {
            float sm = rs[r];
            for (int off = 8; off >= 1; off >>= 1)
                sm += __shfl_xor(sm, off);
            lst[r] = lst[r] * alpha[r] + sm;
            for (int nd = 0; nd < 4; nd++) oacc[nd][r] *= alpha[r];
        }

        // ---- O += P V from LDS ----
        for (int kk = 0; kk < 4; kk++) {
            const int swv = (((kk * 4 + quad) ^ swx) << 3);
            bf16x8 vfa[4];
            for (int nd = 0; nd < 4; nd++)
                vfa[nd] = *(const bf16x8*)&Vs[(nd * 16 + l16) * 128 + swv];
            bf16x8 pf = *(const bf16x8*)&Ps[w][l16 * 128 +
                (((kk * 4 + quad) ^ l16) << 3)];
            for (int nd = 0; nd < 4; nd++)
                oacc[nd] = __builtin_amdgcn_mfma_f32_16x16x32_bf16(
                    pf, vfa[nd], oacc[nd], 0, 0, 0);
        }

        // ---- B2 + stage next V tile (single buffer; readers are done) ----
        if (jk + 1 < nkt) {
            __syncthreads();
            const u16* vn = vg + (size_t)(jk + 1) * 128;
            for (int r = 0; r < 4; r++)
                gld16(vn + voff[r], &Vs[ksidx[r] * 8]);
        }
    }

    for (int nd = 0; nd < 4; nd++)
        for (int r = 0; r < 4; r++) {
            int row = sb * 64 + w * 16 + quad * 4 + r;
            int col = nd * 16 + l16;
            Y[base + (size_t)row * DD + col] = f2b(oacc[nd][r] / lst[r]);
        }
}

extern "C" void kernel_launch(void* const* d_in, const int* in_sizes, int n_in,
                              void* d_out, int out_size, void* d_ws, size_t ws_size,
                              hipStream_t stream) {
    const float* x      = (const float*)d_in[0];   // [2,2048,1024] fp32
    const float* W_attn = (const float*)d_in[1];   // [1024,3072]  fp32
    const float* W_proj = (const float*)d_in[2];   // [1024,1024]  fp32
    float* out = (float*)d_out;                    // [2,2048,1024] fp32

    u16* Wt_attn = (u16*)d_ws;                    // 3072*1024
    u16* Wt_proj = Wt_attn + 3072 * 1024;         // 1024*1024
    u16* xb      = Wt_proj + 1024 * 1024;         // 4096*1024 (reused as vt)
    u16* q       = xb + (size_t)MM * CC;
    u16* k       = q + (size_t)32 * 2048 * 64;
    u16* v       = k + (size_t)32 * 2048 * 64;
    u16* y       = v + (size_t)32 * 2048 * 64;
    u16* vt      = xb;                            // dead after gemm<0>

    cvt_x_k<<<dim3(MM * CC / 1024), 256, 0, stream>>>(x, xb);
    transpose_cvt_k<<<dim3(3072 / 64, 1024 / 64), dim3(64, 4), 0, stream>>>(
        W_attn, Wt_attn, 1024, 3072);
    transpose_cvt_k<<<dim3(1024 / 64, 1024 / 64), dim3(64, 4), 0, stream>>>(
        W_proj, Wt_proj, 1024, 1024);
    gemm_k<0><<<dim3(MM / 128, 3072 / 128), 256, 0, stream>>>(
        xb, Wt_attn, q, k, v, nullptr, 3072, 1024);
    transpose_v_k<<<dim3(TT / 64, BB * HH), dim3(64, 4), 0, stream>>>(v, vt);
    attn_k<<<dim3(32, 32), 256, 0, stream>>>(q, k, vt, y);
    gemm_k<1><<<dim3(MM / 128, 1024 / 128), 256, 0, stream>>>(
        y, Wt_proj, nullptr, nullptr, nullptr, out, 1024, 1024);
}